// Round 14
// baseline (556.356 us; speedup 1.0000x reference)
//
#include <hip/hip_runtime.h>
#include <hip/hip_bf16.h>

constexpr int NN = 50000;
constexpr int NE = 1600000;
constexpr int DI = 512;
constexpr int DH = 256;
constexpr int DO = 64;

constexpr int NC = NN * 16;                 // 800k (row,colchunk) cursor keys
constexpr int G1_BLOCKS = ((NN + 127) / 128) * (DH / 128);  // 782
constexpr int SC_BLOCKS = 2048;
constexpr int SCAN_BLOCKS = (NN + 1023) / 1024;   // 49
constexpr int E4_CAP = NE + NN * 16 + 64;   // rows padded to 16-multiples

constexpr int SP1_BLOCKS = 1024;            // co-resident (4 blocks/CU)
constexpr int SP1_GROUPS = SP1_BLOCKS / 8;  // 128 row-groups x 8 segs
constexpr int SP1_RPG = (NN + SP1_GROUPS - 1) / SP1_GROUPS;  // 391

constexpr int SP2_BLOCKS = 1024;
constexpr int SP2_GROUPS = SP2_BLOCKS / 4;  // 256 row-groups x 4 segs
constexpr int SP2_RPG = (NN + SP2_GROUPS - 1) / SP2_GROUPS;  // 196

typedef __attribute__((ext_vector_type(8))) short short8;
typedef __attribute__((ext_vector_type(4))) float f32x4;

__device__ inline ushort f2b(float f) {          // fp32 -> bf16 bits, RNE
    uint u = __float_as_uint(f);
    u += 0x7fffu + ((u >> 16) & 1u);
    return (ushort)(u >> 16);
}
__device__ inline float b2f(ushort u) {
    return __uint_as_float((uint)u << 16);
}
__device__ inline void gload16(const void* g, void* l) {
    __builtin_amdgcn_global_load_lds(
        (const __attribute__((address_space(1))) unsigned int*)g,
        (__attribute__((address_space(3))) unsigned int*)l, 16, 0, 0);
}

// ---------------- prep (fat): X->bf16 + W1->bf16^T  ||  hist atomics ----------------

__global__ void k_prep(const float* __restrict__ X, ushort* __restrict__ Xb,
                       const float* __restrict__ W1, ushort* __restrict__ w1bT,
                       const int* __restrict__ er, const int* __restrict__ ec,
                       int* __restrict__ counts2) {
    const int bid = blockIdx.x;
    const int tid = threadIdx.x;
    if (bid < 1024) {
        const float4* x4 = (const float4*)X;
        ushort4* o4 = (ushort4*)Xb;
        const int stride = 1024 * 256;
        for (int i = bid * 256 + tid; i < NN * DI / 4; i += stride) {
            float4 v = x4[i];
            o4[i] = make_ushort4(f2b(v.x), f2b(v.y), f2b(v.z), f2b(v.w));
        }
        for (int i = bid * 256 + tid; i < DI * DH; i += stride) {
            int n = i >> 9, k = i & 511;
            w1bT[i] = f2b(W1[(size_t)k * DH + n]);
        }
    } else {
        const int4* r4 = (const int4*)er;
        const int4* c4 = (const int4*)ec;
        const int stride = 1024 * 256;
        for (int i = (bid - 1024) * 256 + tid; i < NE / 4; i += stride) {
            int4 r = r4[i];
            int4 c = c4[i];
            atomicAdd(&counts2[(r.x << 4) | (c.x >> 12)], 1);
            atomicAdd(&counts2[(r.y << 4) | (c.y >> 12)], 1);
            atomicAdd(&counts2[(r.z << 4) | (c.z >> 12)], 1);
            atomicAdd(&counts2[(r.w << 4) | (c.w >> 12)], 1);
        }
    }
}

// ---------------- parallel scan: one THREAD per row ----------------

__global__ __launch_bounds__(1024) void k_scanA(const int* __restrict__ counts2,
                                                int* __restrict__ rp,
                                                int* __restrict__ partials) {
    const int t = threadIdx.x;
    const int r = blockIdx.x * 1024 + t;
    int s = 0;
    if (r < NN) {
        const int4* c4 = (const int4*)(counts2 + (size_t)r * 16);
        int4 a = c4[0], b = c4[1], c = c4[2], d = c4[3];
        s = a.x + a.y + a.z + a.w + b.x + b.y + b.z + b.w
          + c.x + c.y + c.z + c.w + d.x + d.y + d.z + d.w;
        s = (s + 15) & ~15;
    }
    __shared__ int buf[1024];
    buf[t] = s;
    __syncthreads();
    for (int off = 1; off < 1024; off <<= 1) {
        int v = (t >= off) ? buf[t - off] : 0;
        __syncthreads();
        buf[t] += v;
        __syncthreads();
    }
    if (r < NN) rp[r] = buf[t] - s;
    if (t == 1023) partials[blockIdx.x] = buf[1023];
}

__global__ __launch_bounds__(64) void k_scanB(int* __restrict__ partials,
                                              int* __restrict__ rp) {
    __shared__ int buf[64];
    int t = threadIdx.x;
    int v = (t < SCAN_BLOCKS) ? partials[t] : 0;
    buf[t] = v;
    __syncthreads();
    for (int off = 1; off < 64; off <<= 1) {
        int x = (t >= off) ? buf[t - off] : 0;
        __syncthreads();
        buf[t] += x;
        __syncthreads();
    }
    if (t < SCAN_BLOCKS) partials[t] = buf[t] - v;
    if (t == 63) rp[NN] = buf[63];
}

__global__ __launch_bounds__(1024) void k_scanC(const int* __restrict__ counts2,
                                                int* __restrict__ rp,
                                                int* __restrict__ cur2,
                                                const int* __restrict__ partials,
                                                const float* __restrict__ W2,
                                                ushort* __restrict__ w2bT) {
    const int t = threadIdx.x;
    const int r = blockIdx.x * 1024 + t;
    if (r < NN) {
        const int off = partials[blockIdx.x];
        const int base = rp[r] + off;
        rp[r] = base;
        const int4* c4 = (const int4*)(counts2 + (size_t)r * 16);
        int4 ca = c4[0], cb = c4[1], cc = c4[2], cd = c4[3];
        int cnt[16] = {ca.x, ca.y, ca.z, ca.w, cb.x, cb.y, cb.z, cb.w,
                       cc.x, cc.y, cc.z, cc.w, cd.x, cd.y, cd.z, cd.w};
        int out[16];
        int rs = 0;
        #pragma unroll
        for (int b = 0; b < 16; ++b) { out[b] = base + rs; rs += cnt[b]; }
        int4* o4 = (int4*)(cur2 + (size_t)r * 16);
        o4[0] = make_int4(out[0],  out[1],  out[2],  out[3]);
        o4[1] = make_int4(out[4],  out[5],  out[6],  out[7]);
        o4[2] = make_int4(out[8],  out[9],  out[10], out[11]);
        o4[3] = make_int4(out[12], out[13], out[14], out[15]);
    }
    if (blockIdx.x == 0) {
        // w2bT[n][k] = bf16(W2[k][n])
        for (int i = t; i < DH * DO; i += 1024) {
            int n = i >> 8, k = i & 255;
            w2bT[i] = f2b(W2[(size_t)k * DO + n]);
        }
    }
}

// ---------------- GEMM1 (MFMA + global_load_lds): h1 = Xb @ W1 + b1 ----------------

__global__ __launch_bounds__(256, 4) void k_gemm1(const ushort* __restrict__ Xb,
                                                  const ushort* __restrict__ w1bT,
                                                  const float* __restrict__ B,
                                                  ushort* __restrict__ H) {
    __shared__ ushort As[128 * 32];
    __shared__ ushort Bs[128 * 32];
    const int bid = blockIdx.x;
    const int bm = (bid >> 1) * 128;
    const int bn = (bid & 1) * 128;
    const int tid = threadIdx.x;
    const int wid = tid >> 6, lane = tid & 63;
    const int wm = wid >> 1, wn = wid & 1;
    const int lr = lane & 15, lg = lane >> 4;

    f32x4 acc[4][4];
    #pragma unroll
    for (int i = 0; i < 4; ++i)
        #pragma unroll
        for (int j = 0; j < 4; ++j)
            acc[i][j] = (f32x4){0.f, 0.f, 0.f, 0.f};

    for (int kt = 0; kt < DI; kt += 32) {
        #pragma unroll
        for (int c = 0; c < 2; ++c) {
            int i = c * 256 + tid;
            int row = i >> 2, slot = i & 3;
            const ushort* g = Xb + (size_t)(bm + row) * DI + kt + slot * 8;
            gload16(g, As + (size_t)(c * 256 + wid * 64) * 8);
        }
        #pragma unroll
        for (int c = 0; c < 2; ++c) {
            int i = c * 256 + tid;
            int row = i >> 2, slot = i & 3;
            const ushort* g = w1bT + (size_t)(bn + row) * DI + kt + slot * 8;
            gload16(g, Bs + (size_t)(c * 256 + wid * 64) * 8);
        }
        __syncthreads();

        short8 a[4], b[4];
        #pragma unroll
        for (int f = 0; f < 4; ++f) {
            a[f] = *(short8*)&As[(wm * 64 + f * 16 + lr) * 32 + lg * 8];
            b[f] = *(short8*)&Bs[(wn * 64 + f * 16 + lr) * 32 + lg * 8];
        }
        #pragma unroll
        for (int i = 0; i < 4; ++i)
            #pragma unroll
            for (int j = 0; j < 4; ++j)
                acc[i][j] = __builtin_amdgcn_mfma_f32_16x16x32_bf16(a[i], b[j], acc[i][j], 0, 0, 0);
        __syncthreads();
    }

    #pragma unroll
    for (int i = 0; i < 4; ++i) {
        int r0 = bm + wm * 64 + i * 16 + lg * 4;
        #pragma unroll
        for (int j = 0; j < 4; ++j) {
            int col = bn + wn * 64 + j * 16 + lr;
            float bias = B[col];
            #pragma unroll
            for (int e = 0; e < 4; ++e) {
                int r = r0 + e;
                if (r < NN) H[(size_t)r * DH + col] = f2b(acc[i][j][e] + bias);
            }
        }
    }
}

// ---------------- scatter (standalone): raw inputs, 800k-key cursors, XCD-windowed ----------------

__global__ __launch_bounds__(256) void k_scatter(const int* __restrict__ er,
                                                 const int* __restrict__ ec,
                                                 const float* __restrict__ ev,
                                                 int* __restrict__ cur2,
                                                 uint* __restrict__ e4) {
    const int g = blockIdx.x & 7;
    const int lo = g * (NN / 8), hi = lo + (NN / 8);
    const int4* r4 = (const int4*)er;
    for (int q = (blockIdx.x >> 3) * 256 + (int)threadIdx.x; q < NE / 4;
         q += (SC_BLOCKS / 8) * 256) {
        int4 r = r4[q];
        #pragma unroll
        for (int e = 0; e < 4; ++e) {
            int rr = (e == 0) ? r.x : (e == 1) ? r.y : (e == 2) ? r.z : r.w;
            if (rr >= lo && rr < hi) {
                int c = ec[q * 4 + e];
                float v = ev[q * 4 + e];
                int p = atomicAdd(&cur2[(rr << 4) | (c >> 12)], 1);
                e4[p] = (uint)c | ((uint)f2b(v) << 16);
            }
        }
    }
}

// ---------------- SpMM1 + ReLU: persistent, dim-seg-split, XCD-pinned ----------------
// 1024 co-resident blocks (4/CU via launch_bounds); seg = bid&7 == XCD (blocks
// never migrate -> per-XCD gather hot set = 50000 x 64 B = 3.2 MB, L2-resident).
// Wave: 8 edge-slots x 8 dq-lanes x ushort4; 16-edge (2x8) pipelined batches.

__global__ __launch_bounds__(256, 4) void k_spmm1p(const int* __restrict__ rp,
                                                   const uint* __restrict__ e4,
                                                   const ushort* __restrict__ H,
                                                   ushort* __restrict__ O) {
    const int seg = blockIdx.x & 7;
    const int grp = blockIdx.x >> 3;
    const int w = threadIdx.x >> 6, lane = threadIdx.x & 63;
    const int slot = lane >> 3;       // 0..7
    const int dq = lane & 7;          // dims seg*32 + dq*4 ..+3
    const ushort* gbase = H + seg * 32 + dq * 4;
    const int r1 = min(grp * SP1_RPG + SP1_RPG, NN);

    for (int r = grp * SP1_RPG + w; r < r1; r += 4) {
        const int s = rp[r], e = rp[r + 1];
        float a0 = 0.f, a1 = 0.f, a2 = 0.f, a3 = 0.f;
        for (int i = s; i < e; i += 16) {
            uint ua = e4[i + slot];
            uint ub = e4[i + 8 + slot];
            ushort4 ha = *(const ushort4*)(gbase + (size_t)(ua & 0xffffu) * DH);
            ushort4 hb = *(const ushort4*)(gbase + (size_t)(ub & 0xffffu) * DH);
            float va = __uint_as_float(ua & 0xffff0000u);
            float vb = __uint_as_float(ub & 0xffff0000u);
            a0 += va * b2f(ha.x) + vb * b2f(hb.x);
            a1 += va * b2f(ha.y) + vb * b2f(hb.y);
            a2 += va * b2f(ha.z) + vb * b2f(hb.z);
            a3 += va * b2f(ha.w) + vb * b2f(hb.w);
        }
        #pragma unroll
        for (int m = 8; m < 64; m <<= 1) {
            a0 += __shfl_xor(a0, m); a1 += __shfl_xor(a1, m);
            a2 += __shfl_xor(a2, m); a3 += __shfl_xor(a3, m);
        }
        if (slot == 0) {
            ushort4 o = make_ushort4(f2b(fmaxf(a0, 0.f)), f2b(fmaxf(a1, 0.f)),
                                     f2b(fmaxf(a2, 0.f)), f2b(fmaxf(a3, 0.f)));
            *(ushort4*)(O + (size_t)r * DH + seg * 32 + dq * 4) = o;
        }
    }
}

// ---------------- GEMM2 (MFMA, standalone): h2 = h1b @ W2 + b2 ----------------

__global__ __launch_bounds__(256) void k_gemm2(const ushort* __restrict__ HB,
                                               const ushort* __restrict__ w2bT,
                                               const float* __restrict__ B2,
                                               ushort* __restrict__ H2) {
    const int tid = threadIdx.x;
    const int wid = tid >> 6, lane = tid & 63;
    const int lr = lane & 15, lg = lane >> 4;
    const int r0 = blockIdx.x * 128 + wid * 32;

    f32x4 acc[2][4];
    #pragma unroll
    for (int i = 0; i < 2; ++i)
        #pragma unroll
        for (int j = 0; j < 4; ++j)
            acc[i][j] = (f32x4){0.f, 0.f, 0.f, 0.f};

    for (int kt = 0; kt < DH; kt += 32) {
        short8 a[2], b[4];
        #pragma unroll
        for (int f = 0; f < 2; ++f) {
            int row = r0 + f * 16 + lr;
            a[f] = (row < NN) ? *(const short8*)(HB + (size_t)row * DH + kt + lg * 8)
                              : (short8){0,0,0,0,0,0,0,0};
        }
        #pragma unroll
        for (int j = 0; j < 4; ++j)
            b[j] = *(const short8*)(w2bT + (size_t)(j * 16 + lr) * DH + kt + lg * 8);
        #pragma unroll
        for (int i = 0; i < 2; ++i)
            #pragma unroll
            for (int j = 0; j < 4; ++j)
                acc[i][j] = __builtin_amdgcn_mfma_f32_16x16x32_bf16(a[i], b[j], acc[i][j], 0, 0, 0);
    }

    #pragma unroll
    for (int i = 0; i < 2; ++i) {
        #pragma unroll
        for (int j = 0; j < 4; ++j) {
            int col = j * 16 + lr;
            float bias = B2[col];
            #pragma unroll
            for (int e = 0; e < 4; ++e) {
                int row = r0 + i * 16 + lg * 4 + e;
                if (row < NN) H2[(size_t)row * DO + col] = f2b(acc[i][j][e] + bias);
            }
        }
    }
}

// ---------------- SpMM2: persistent, dim-seg-split (seg = bid&3) ----------------
// XCDs {s, s+4} share seg s; per-XCD hot set = 50000 x 32 B = 1.6 MB.

__global__ __launch_bounds__(256, 4) void k_spmm_outp(const int* __restrict__ rp,
                                                      const uint* __restrict__ e4,
                                                      const ushort* __restrict__ H2,
                                                      float* __restrict__ OUT) {
    const int seg = blockIdx.x & 3;
    const int grp = blockIdx.x >> 2;
    const int w = threadIdx.x >> 6, lane = threadIdx.x & 63;
    const int slot = lane >> 2;       // 0..15
    const int dq = lane & 3;          // dims seg*16 + dq*4 ..+3
    const ushort* gbase = H2 + seg * 16 + dq * 4;
    const int r1 = min(grp * SP2_RPG + SP2_RPG, NN);

    for (int r = grp * SP2_RPG + w; r < r1; r += 4) {
        const int s = rp[r], e = rp[r + 1];
        float a0 = 0.f, a1 = 0.f, a2 = 0.f, a3 = 0.f;
        for (int i = s; i < e; i += 16) {
            uint u = e4[i + slot];
            ushort4 h = *(const ushort4*)(gbase + (size_t)(u & 0xffffu) * DO);
            float v = __uint_as_float(u & 0xffff0000u);
            a0 += v * b2f(h.x); a1 += v * b2f(h.y);
            a2 += v * b2f(h.z); a3 += v * b2f(h.w);
        }
        #pragma unroll
        for (int m = 4; m < 64; m <<= 1) {
            a0 += __shfl_xor(a0, m); a1 += __shfl_xor(a1, m);
            a2 += __shfl_xor(a2, m); a3 += __shfl_xor(a3, m);
        }
        if (slot == 0) {
            *(float4*)(OUT + (size_t)r * DO + seg * 16 + dq * 4) =
                make_float4(a0, a1, a2, a3);
        }
    }
}

// ---------------- launch ----------------

extern "C" void kernel_launch(void* const* d_in, const int* in_sizes, int n_in,
                              void* d_out, int out_size, void* d_ws, size_t ws_size,
                              hipStream_t stream) {
    const float* x  = (const float*)d_in[0];
    const int*   er = (const int*)d_in[1];
    const int*   ec = (const int*)d_in[2];
    const float* ev = (const float*)d_in[3];
    const float* W1 = (const float*)d_in[4];
    const float* b1 = (const float*)d_in[5];
    const float* W2 = (const float*)d_in[6];
    const float* b2 = (const float*)d_in[7];
    float* out = (float*)d_out;

    char* ws = (char*)d_ws;
    // Xb (51.2 MB) is dead after k_gemm1; e4 (9.6 MB, offset 0) and h1b
    // (25.6 MB, offset 12 MB) both alias it — written strictly after gemm1.
    ushort* Xb  = (ushort*)ws;
    uint*   e4  = (uint*)ws;
    ushort* h1b = (ushort*)(ws + (size_t)12 * 1024 * 1024);
    ws += (size_t)NN * DI * 2;                                               // 51.2 MB
    ushort* h1  = (ushort*)ws; ws += (size_t)NN * DH * 2;                    // 25.6 MB
    ushort* h2  = (ushort*)ws; ws += (size_t)NN * DO * 2;                    //  6.4 MB
    int* counts2 = (int*)ws;   ws += ((size_t)NC * 4 + 255) & ~(size_t)255;  //  3.2 MB
    int* rp     = (int*)ws;    ws += ((size_t)(NN + 1) * 4 + 255) & ~(size_t)255;
    int* cur2   = (int*)ws;    ws += ((size_t)NC * 4 + 255) & ~(size_t)255;  //  3.2 MB
    int* partials = (int*)ws;  ws += 256;
    ushort* w1bT = (ushort*)ws; ws += ((size_t)DI * DH * 2 + 255) & ~(size_t)255;
    ushort* w2bT = (ushort*)ws; ws += ((size_t)DH * DO * 2 + 255) & ~(size_t)255;

    hipMemsetAsync(counts2, 0, (size_t)NC * 4, stream);
    k_prep<<<2048, 256, 0, stream>>>(x, Xb, W1, w1bT, er, ec, counts2);
    k_scanA<<<SCAN_BLOCKS, 1024, 0, stream>>>(counts2, rp, partials);
    k_scanB<<<1, 64, 0, stream>>>(partials, rp);
    k_scanC<<<SCAN_BLOCKS, 1024, 0, stream>>>(counts2, rp, cur2, partials, W2, w2bT);
    k_gemm1<<<G1_BLOCKS, 256, 0, stream>>>(Xb, w1bT, b1, h1);
    hipMemsetAsync(e4, 0, (size_t)E4_CAP * 4, stream);      // after gemm1 (aliases Xb)
    k_scatter<<<SC_BLOCKS, 256, 0, stream>>>(er, ec, ev, cur2, e4);
    k_spmm1p<<<SP1_BLOCKS, 256, 0, stream>>>(rp, e4, h1, h1b);
    k_gemm2<<<(NN + 127) / 128, 256, 0, stream>>>(h1b, w2bT, b2, h2);
    k_spmm_outp<<<SP2_BLOCKS, 256, 0, stream>>>(rp, e4, h2, out);
}

// Round 15
// 328.488 us; speedup vs baseline: 1.6937x; 1.6937x over previous
//
#include <hip/hip_runtime.h>
#include <hip/hip_bf16.h>

constexpr int NN = 50000;
constexpr int NE = 1600000;
constexpr int DI = 512;
constexpr int DH = 256;
constexpr int DO = 64;

constexpr int NC = NN * 16;                 // 800k (row,colchunk) cursor keys
constexpr int G1_BLOCKS = ((NN + 127) / 128) * (DH / 128);  // 782
constexpr int SC_BLOCKS = 2048;
constexpr int SCAN_BLOCKS = (NN + 1023) / 1024;   // 49
constexpr int E4_CAP = NE + NN * 16 + 64;   // rows padded to 16-multiples

typedef __attribute__((ext_vector_type(8))) short short8;
typedef __attribute__((ext_vector_type(4))) float f32x4;

__device__ inline ushort f2b(float f) {          // fp32 -> bf16 bits, RNE
    uint u = __float_as_uint(f);
    u += 0x7fffu + ((u >> 16) & 1u);
    return (ushort)(u >> 16);
}
__device__ inline float b2f(ushort u) {
    return __uint_as_float((uint)u << 16);
}
__device__ inline void gload16(const void* g, void* l) {
    __builtin_amdgcn_global_load_lds(
        (const __attribute__((address_space(1))) unsigned int*)g,
        (__attribute__((address_space(3))) unsigned int*)l, 16, 0, 0);
}

// ---------------- prep (fat): X->bf16 + W1->bf16^T + rc32 pack || hist atomics ----------------

__global__ void k_prep(const float* __restrict__ X, ushort* __restrict__ Xb,
                       const float* __restrict__ W1, ushort* __restrict__ w1bT,
                       const int* __restrict__ er, const int* __restrict__ ec,
                       int* __restrict__ counts2, uint* __restrict__ rc32) {
    const int bid = blockIdx.x;
    const int tid = threadIdx.x;
    if (bid < 1024) {
        const float4* x4 = (const float4*)X;
        ushort4* o4 = (ushort4*)Xb;
        const int stride = 1024 * 256;
        for (int i = bid * 256 + tid; i < NN * DI / 4; i += stride) {
            float4 v = x4[i];
            o4[i] = make_ushort4(f2b(v.x), f2b(v.y), f2b(v.z), f2b(v.w));
        }
        for (int i = bid * 256 + tid; i < DI * DH; i += stride) {
            int n = i >> 9, k = i & 511;
            w1bT[i] = f2b(W1[(size_t)k * DH + n]);
        }
    } else {
        const int4* r4 = (const int4*)er;
        const int4* c4 = (const int4*)ec;
        const int stride = 1024 * 256;
        for (int i = (bid - 1024) * 256 + tid; i < NE / 4; i += stride) {
            int4 r = r4[i];
            int4 c = c4[i];
            *(uint4*)&rc32[i * 4] = make_uint4(
                ((uint)r.x << 16) | (uint)c.x, ((uint)r.y << 16) | (uint)c.y,
                ((uint)r.z << 16) | (uint)c.z, ((uint)r.w << 16) | (uint)c.w);
            atomicAdd(&counts2[(r.x << 4) | (c.x >> 12)], 1);
            atomicAdd(&counts2[(r.y << 4) | (c.y >> 12)], 1);
            atomicAdd(&counts2[(r.z << 4) | (c.z >> 12)], 1);
            atomicAdd(&counts2[(r.w << 4) | (c.w >> 12)], 1);
        }
    }
}

// ---------------- parallel scan: one THREAD per row ----------------

__global__ __launch_bounds__(1024) void k_scanA(const int* __restrict__ counts2,
                                                int* __restrict__ rp,
                                                int* __restrict__ partials) {
    const int t = threadIdx.x;
    const int r = blockIdx.x * 1024 + t;
    int s = 0;
    if (r < NN) {
        const int4* c4 = (const int4*)(counts2 + (size_t)r * 16);
        int4 a = c4[0], b = c4[1], c = c4[2], d = c4[3];
        s = a.x + a.y + a.z + a.w + b.x + b.y + b.z + b.w
          + c.x + c.y + c.z + c.w + d.x + d.y + d.z + d.w;
        s = (s + 15) & ~15;
    }
    __shared__ int buf[1024];
    buf[t] = s;
    __syncthreads();
    for (int off = 1; off < 1024; off <<= 1) {
        int v = (t >= off) ? buf[t - off] : 0;
        __syncthreads();
        buf[t] += v;
        __syncthreads();
    }
    if (r < NN) rp[r] = buf[t] - s;
    if (t == 1023) partials[blockIdx.x] = buf[1023];
}

__global__ __launch_bounds__(64) void k_scanB(int* __restrict__ partials,
                                              int* __restrict__ rp) {
    __shared__ int buf[64];
    int t = threadIdx.x;
    int v = (t < SCAN_BLOCKS) ? partials[t] : 0;
    buf[t] = v;
    __syncthreads();
    for (int off = 1; off < 64; off <<= 1) {
        int x = (t >= off) ? buf[t - off] : 0;
        __syncthreads();
        buf[t] += x;
        __syncthreads();
    }
    if (t < SCAN_BLOCKS) partials[t] = buf[t] - v;
    if (t == 63) rp[NN] = buf[63];
}

__global__ __launch_bounds__(1024) void k_scanC(const int* __restrict__ counts2,
                                                int* __restrict__ rp,
                                                int* __restrict__ cur2,
                                                const int* __restrict__ partials,
                                                const float* __restrict__ W2,
                                                ushort* __restrict__ w2bT) {
    const int t = threadIdx.x;
    const int r = blockIdx.x * 1024 + t;
    if (r < NN) {
        const int off = partials[blockIdx.x];
        const int base = rp[r] + off;
        rp[r] = base;
        const int4* c4 = (const int4*)(counts2 + (size_t)r * 16);
        int4 ca = c4[0], cb = c4[1], cc = c4[2], cd = c4[3];
        int cnt[16] = {ca.x, ca.y, ca.z, ca.w, cb.x, cb.y, cb.z, cb.w,
                       cc.x, cc.y, cc.z, cc.w, cd.x, cd.y, cd.z, cd.w};
        int out[16];
        int rs = 0;
        #pragma unroll
        for (int b = 0; b < 16; ++b) { out[b] = base + rs; rs += cnt[b]; }
        int4* o4 = (int4*)(cur2 + (size_t)r * 16);
        o4[0] = make_int4(out[0],  out[1],  out[2],  out[3]);
        o4[1] = make_int4(out[4],  out[5],  out[6],  out[7]);
        o4[2] = make_int4(out[8],  out[9],  out[10], out[11]);
        o4[3] = make_int4(out[12], out[13], out[14], out[15]);
    }
    if (blockIdx.x == 0) {
        // w2bT[n][k] = bf16(W2[k][n])
        for (int i = t; i < DH * DO; i += 1024) {
            int n = i >> 8, k = i & 255;
            w2bT[i] = f2b(W2[(size_t)k * DO + n]);
        }
    }
}

// ---------------- GEMM1 (MFMA + global_load_lds): h1 = Xb @ W1 + b1 ----------------

__global__ __launch_bounds__(256, 4) void k_gemm1(const ushort* __restrict__ Xb,
                                                  const ushort* __restrict__ w1bT,
                                                  const float* __restrict__ B,
                                                  ushort* __restrict__ H) {
    __shared__ ushort As[128 * 32];
    __shared__ ushort Bs[128 * 32];
    const int bid = blockIdx.x;
    const int bm = (bid >> 1) * 128;
    const int bn = (bid & 1) * 128;
    const int tid = threadIdx.x;
    const int wid = tid >> 6, lane = tid & 63;
    const int wm = wid >> 1, wn = wid & 1;
    const int lr = lane & 15, lg = lane >> 4;

    f32x4 acc[4][4];
    #pragma unroll
    for (int i = 0; i < 4; ++i)
        #pragma unroll
        for (int j = 0; j < 4; ++j)
            acc[i][j] = (f32x4){0.f, 0.f, 0.f, 0.f};

    for (int kt = 0; kt < DI; kt += 32) {
        #pragma unroll
        for (int c = 0; c < 2; ++c) {
            int i = c * 256 + tid;
            int row = i >> 2, slot = i & 3;
            const ushort* g = Xb + (size_t)(bm + row) * DI + kt + slot * 8;
            gload16(g, As + (size_t)(c * 256 + wid * 64) * 8);
        }
        #pragma unroll
        for (int c = 0; c < 2; ++c) {
            int i = c * 256 + tid;
            int row = i >> 2, slot = i & 3;
            const ushort* g = w1bT + (size_t)(bn + row) * DI + kt + slot * 8;
            gload16(g, Bs + (size_t)(c * 256 + wid * 64) * 8);
        }
        __syncthreads();

        short8 a[4], b[4];
        #pragma unroll
        for (int f = 0; f < 4; ++f) {
            a[f] = *(short8*)&As[(wm * 64 + f * 16 + lr) * 32 + lg * 8];
            b[f] = *(short8*)&Bs[(wn * 64 + f * 16 + lr) * 32 + lg * 8];
        }
        #pragma unroll
        for (int i = 0; i < 4; ++i)
            #pragma unroll
            for (int j = 0; j < 4; ++j)
                acc[i][j] = __builtin_amdgcn_mfma_f32_16x16x32_bf16(a[i], b[j], acc[i][j], 0, 0, 0);
        __syncthreads();
    }

    #pragma unroll
    for (int i = 0; i < 4; ++i) {
        int r0 = bm + wm * 64 + i * 16 + lg * 4;
        #pragma unroll
        for (int j = 0; j < 4; ++j) {
            int col = bn + wn * 64 + j * 16 + lr;
            float bias = B[col];
            #pragma unroll
            for (int e = 0; e < 4; ++e) {
                int r = r0 + e;
                if (r < NN) H[(size_t)r * DH + col] = f2b(acc[i][j][e] + bias);
            }
        }
    }
}

// ---------------- scatter: rc32-packed (8x re-read = 51 MB), XCD-windowed ----------------

__global__ __launch_bounds__(256) void k_scatter(const uint* __restrict__ rc32,
                                                 const float* __restrict__ ev,
                                                 int* __restrict__ cur2,
                                                 uint* __restrict__ e4) {
    const int g = blockIdx.x & 7;
    const uint lo = g * (NN / 8), hi = lo + (NN / 8);
    const uint4* rc4 = (const uint4*)rc32;
    for (int q = (blockIdx.x >> 3) * 256 + (int)threadIdx.x; q < NE / 4;
         q += (SC_BLOCKS / 8) * 256) {
        uint4 t = rc4[q];
        #pragma unroll
        for (int e = 0; e < 4; ++e) {
            uint rc = (e == 0) ? t.x : (e == 1) ? t.y : (e == 2) ? t.z : t.w;
            uint rr = rc >> 16;
            if (rr >= lo && rr < hi) {
                uint c = rc & 0xffffu;
                float v = ev[q * 4 + e];
                int p = atomicAdd(&cur2[(rr << 4) | (c >> 12)], 1);
                e4[p] = c | ((uint)f2b(v) << 16);
            }
        }
    }
}

// ---------------- fused SpMM1 + ReLU + GEMM2(MFMA) — r13 version ----------------

__global__ __launch_bounds__(256) void k_srg(const int* __restrict__ rp,
                                             const uint* __restrict__ e4,
                                             const ushort* __restrict__ H,
                                             const ushort* __restrict__ w2bT,
                                             const float* __restrict__ B2,
                                             ushort* __restrict__ H2) {
    __shared__ ushort hs[16][264];
    const int tid = threadIdx.x;
    const int w = tid >> 6, lane = tid & 63;
    const int half = lane >> 5;
    const int dl = lane & 31;
    const ushort* gbase = H + dl * 8;
    const uint4* eq = (const uint4*)e4;

    #pragma unroll
    for (int q = 0; q < 4; ++q) {
        const int r = blockIdx.x * 16 + w * 4 + q;
        const int s = rp[r], e = rp[r + 1];
        float a[8] = {0.f, 0.f, 0.f, 0.f, 0.f, 0.f, 0.f, 0.f};

        int qi = s >> 2;
        uint4 q0 = eq[qi], q1 = eq[qi + 1], q2 = eq[qi + 2], q3 = eq[qi + 3];
        for (int i = s; i < e; i += 16) {
            uint u[8];
            u[0] = half ? q0.y : q0.x;  u[1] = half ? q0.w : q0.z;
            u[2] = half ? q1.y : q1.x;  u[3] = half ? q1.w : q1.z;
            u[4] = half ? q2.y : q2.x;  u[5] = half ? q2.w : q2.z;
            u[6] = half ? q3.y : q3.x;  u[7] = half ? q3.w : q3.z;
            uint4 hw[8];
            #pragma unroll
            for (int k = 0; k < 8; ++k)
                hw[k] = *(const uint4*)(gbase + (size_t)(u[k] & 0xffffu) * DH);
            qi += 4;
            q0 = eq[qi]; q1 = eq[qi + 1]; q2 = eq[qi + 2]; q3 = eq[qi + 3];
            #pragma unroll
            for (int k = 0; k < 8; ++k) {
                float v = __uint_as_float(u[k] & 0xffff0000u);
                uint w0 = hw[k].x, w1 = hw[k].y, w2 = hw[k].z, w3 = hw[k].w;
                a[0] += v * __uint_as_float(w0 << 16);
                a[1] += v * __uint_as_float(w0 & 0xffff0000u);
                a[2] += v * __uint_as_float(w1 << 16);
                a[3] += v * __uint_as_float(w1 & 0xffff0000u);
                a[4] += v * __uint_as_float(w2 << 16);
                a[5] += v * __uint_as_float(w2 & 0xffff0000u);
                a[6] += v * __uint_as_float(w3 << 16);
                a[7] += v * __uint_as_float(w3 & 0xffff0000u);
            }
        }
        #pragma unroll
        for (int d = 0; d < 8; ++d) a[d] += __shfl_xor(a[d], 32);
        if (half == 0) {
            short8 o;
            #pragma unroll
            for (int d = 0; d < 8; ++d) o[d] = (short)f2b(fmaxf(a[d], 0.f));
            *(short8*)&hs[w * 4 + q][dl * 8] = o;
        }
    }
    __syncthreads();

    // phase 2: wave w -> output cols [w*16, w*16+16)
    const int lr = lane & 15, lg = lane >> 4;
    f32x4 acc = (f32x4){0.f, 0.f, 0.f, 0.f};
    #pragma unroll
    for (int kt = 0; kt < DH; kt += 32) {
        short8 af = *(short8*)&hs[lr][kt + lg * 8];
        short8 bf = *(const short8*)(w2bT + (size_t)(w * 16 + lr) * DH + kt + lg * 8);
        acc = __builtin_amdgcn_mfma_f32_16x16x32_bf16(af, bf, acc, 0, 0, 0);
    }
    const int col = w * 16 + lr;
    const float bias = B2[col];
    #pragma unroll
    for (int e = 0; e < 4; ++e) {
        int row = blockIdx.x * 16 + lg * 4 + e;
        H2[(size_t)row * DO + col] = f2b(acc[e] + bias);
    }
}

// ---------------- SpMM2: out = A @ h2 (h2 3.2 MB L2-fits everywhere; e4 read 1x) ----------------
// wave = 8 edge slots x 8 dim-lanes (short8 = 16 B); padded rows -> no tail.

__global__ __launch_bounds__(256) void k_spmm_out(const int* __restrict__ rp,
                                                  const uint* __restrict__ e4,
                                                  const ushort* __restrict__ H2,
                                                  float* __restrict__ OUT) {
    const int r = blockIdx.x * 4 + (threadIdx.x >> 6);
    const int lane = threadIdx.x & 63;
    const int slot = lane >> 3;       // 0..7: edges i+2*slot, i+2*slot+1
    const int dq = lane & 7;          // dims 8*dq .. 8*dq+7
    const int s = rp[r], e = rp[r + 1];
    const ushort* base = H2 + dq * 8;
    float a[8] = {0.f, 0.f, 0.f, 0.f, 0.f, 0.f, 0.f, 0.f};

    for (int i = s; i < e; i += 16) {
        uint2 u = *(const uint2*)(e4 + i + 2 * slot);
        short8 h0 = *(const short8*)(base + (size_t)(u.x & 0xffffu) * DO);
        short8 h1 = *(const short8*)(base + (size_t)(u.y & 0xffffu) * DO);
        float v0 = __uint_as_float(u.x & 0xffff0000u);
        float v1 = __uint_as_float(u.y & 0xffff0000u);
        #pragma unroll
        for (int d = 0; d < 8; ++d)
            a[d] += v0 * b2f((ushort)h0[d]) + v1 * b2f((ushort)h1[d]);
    }
    #pragma unroll
    for (int d = 0; d < 8; ++d) {
        a[d] += __shfl_xor(a[d], 8);
        a[d] += __shfl_xor(a[d], 16);
        a[d] += __shfl_xor(a[d], 32);
    }
    if (slot == 0) {
        float* o = OUT + (size_t)r * DO + dq * 8;
        *(float4*)o       = make_float4(a[0], a[1], a[2], a[3]);
        *(float4*)(o + 4) = make_float4(a[4], a[5], a[6], a[7]);
    }
}

// ---------------- launch ----------------

extern "C" void kernel_launch(void* const* d_in, const int* in_sizes, int n_in,
                              void* d_out, int out_size, void* d_ws, size_t ws_size,
                              hipStream_t stream) {
    const float* x  = (const float*)d_in[0];
    const int*   er = (const int*)d_in[1];
    const int*   ec = (const int*)d_in[2];
    const float* ev = (const float*)d_in[3];
    const float* W1 = (const float*)d_in[4];
    const float* b1 = (const float*)d_in[5];
    const float* W2 = (const float*)d_in[6];
    const float* b2 = (const float*)d_in[7];
    float* out = (float*)d_out;

    char* ws = (char*)d_ws;
    // Aliasing: e4 (9.6 MB) overlays Xb (dead after gemm1; memset+scatter run
    // after). rc32 (6.4 MB) overlays h2 (h2 first written by k_srg, which runs
    // after scatter has finished reading rc32).
    ushort* Xb  = (ushort*)ws;
    uint*   e4  = (uint*)ws;
    ws += (size_t)NN * DI * 2;                                               // 51.2 MB
    ushort* h1  = (ushort*)ws; ws += (size_t)NN * DH * 2;                    // 25.6 MB
    ushort* h2  = (ushort*)ws;
    uint*   rc32 = (uint*)ws;  ws += (size_t)NN * DO * 2;                    //  6.4 MB
    int* counts2 = (int*)ws;   ws += ((size_t)NC * 4 + 255) & ~(size_t)255;  //  3.2 MB
    int* rp     = (int*)ws;    ws += ((size_t)(NN + 1) * 4 + 255) & ~(size_t)255;
    int* cur2   = (int*)ws;    ws += ((size_t)NC * 4 + 255) & ~(size_t)255;  //  3.2 MB
    int* partials = (int*)ws;  ws += 256;
    ushort* w1bT = (ushort*)ws; ws += ((size_t)DI * DH * 2 + 255) & ~(size_t)255;
    ushort* w2bT = (ushort*)ws; ws += ((size_t)DH * DO * 2 + 255) & ~(size_t)255;

    hipMemsetAsync(counts2, 0, (size_t)NC * 4, stream);
    k_prep<<<2048, 256, 0, stream>>>(x, Xb, W1, w1bT, er, ec, counts2, rc32);
    k_scanA<<<SCAN_BLOCKS, 1024, 0, stream>>>(counts2, rp, partials);
    k_scanB<<<1, 64, 0, stream>>>(partials, rp);
    k_scanC<<<SCAN_BLOCKS, 1024, 0, stream>>>(counts2, rp, cur2, partials, W2, w2bT);
    k_gemm1<<<G1_BLOCKS, 256, 0, stream>>>(Xb, w1bT, b1, h1);
    hipMemsetAsync(e4, 0, (size_t)E4_CAP * 4, stream);      // after gemm1 (aliases Xb)
    k_scatter<<<SC_BLOCKS, 256, 0, stream>>>(rc32, ev, cur2, e4);
    k_srg<<<NN / 16, 256, 0, stream>>>(rp, e4, h1, w2bT, b2, h2);
    k_spmm_out<<<NN / 4, 256, 0, stream>>>(rp, e4, h2, out);
}

// Round 16
// 322.733 us; speedup vs baseline: 1.7239x; 1.0178x over previous
//
#include <hip/hip_runtime.h>
#include <hip/hip_bf16.h>

constexpr int NN = 50000;
constexpr int NE = 1600000;
constexpr int DI = 512;
constexpr int DH = 256;
constexpr int DO = 64;

constexpr int NC = NN * 16;                 // 800k (row,colchunk) cursor keys
constexpr int G1_BLOCKS = ((NN + 127) / 128) * (DH / 128);  // 782
constexpr int SC_BLOCKS = 2048;
constexpr int SCAN_BLOCKS = (NN + 1023) / 1024;   // 49
constexpr int E4_CAP = NE + NN * 16 + 64;   // rows padded to 16-multiples

typedef __attribute__((ext_vector_type(8))) short short8;
typedef __attribute__((ext_vector_type(4))) float f32x4;

__device__ inline ushort f2b(float f) {          // fp32 -> bf16 bits, RNE
    uint u = __float_as_uint(f);
    u += 0x7fffu + ((u >> 16) & 1u);
    return (ushort)(u >> 16);
}
__device__ inline float b2f(ushort u) {
    return __uint_as_float((uint)u << 16);
}
__device__ inline void gload16(const void* g, void* l) {
    __builtin_amdgcn_global_load_lds(
        (const __attribute__((address_space(1))) unsigned int*)g,
        (__attribute__((address_space(3))) unsigned int*)l, 16, 0, 0);
}

// ---------------- prep (fat): X->bf16 || edge pass (rc32+evb+hist) + W converts ----------------

__global__ void k_prep(const float* __restrict__ X, ushort* __restrict__ Xb,
                       const float* __restrict__ W1, ushort* __restrict__ w1bT,
                       const float* __restrict__ W2, ushort* __restrict__ w2bT,
                       const int* __restrict__ er, const int* __restrict__ ec,
                       const float* __restrict__ ev,
                       int* __restrict__ counts2, uint* __restrict__ rc32,
                       ushort* __restrict__ evb) {
    const int bid = blockIdx.x;
    const int tid = threadIdx.x;
    if (bid < 1024) {
        const float4* x4 = (const float4*)X;
        ushort4* o4 = (ushort4*)Xb;
        const int stride = 1024 * 256;
        for (int i = bid * 256 + tid; i < NN * DI / 4; i += stride) {
            float4 v = x4[i];
            o4[i] = make_ushort4(f2b(v.x), f2b(v.y), f2b(v.z), f2b(v.w));
        }
    } else {
        const int b = bid - 1024;
        const int stride = 1024 * 256;
        const int4* r4 = (const int4*)er;
        const int4* c4 = (const int4*)ec;
        const float4* v4 = (const float4*)ev;
        for (int i = b * 256 + tid; i < NE / 4; i += stride) {
            int4 r = r4[i];
            int4 c = c4[i];
            float4 v = v4[i];
            *(uint4*)&rc32[i * 4] = make_uint4(
                ((uint)r.x << 16) | (uint)c.x, ((uint)r.y << 16) | (uint)c.y,
                ((uint)r.z << 16) | (uint)c.z, ((uint)r.w << 16) | (uint)c.w);
            *(ushort4*)&evb[i * 4] =
                make_ushort4(f2b(v.x), f2b(v.y), f2b(v.z), f2b(v.w));
            atomicAdd(&counts2[(r.x << 4) | (c.x >> 12)], 1);
            atomicAdd(&counts2[(r.y << 4) | (c.y >> 12)], 1);
            atomicAdd(&counts2[(r.z << 4) | (c.z >> 12)], 1);
            atomicAdd(&counts2[(r.w << 4) | (c.w >> 12)], 1);
        }
        // w1bT[n][k] = bf16(W1[k][n]); w2bT[n][k] = bf16(W2[k][n])
        for (int i = b * 256 + tid; i < DI * DH; i += stride) {
            int n = i >> 9, k = i & 511;
            w1bT[i] = f2b(W1[(size_t)k * DH + n]);
        }
        for (int i = b * 256 + tid; i < DH * DO; i += stride) {
            int n = i >> 8, k = i & 255;
            w2bT[i] = f2b(W2[(size_t)k * DO + n]);
        }
    }
}

// ---------------- parallel scan: one THREAD per row ----------------

__global__ __launch_bounds__(1024) void k_scanA(const int* __restrict__ counts2,
                                                int* __restrict__ rp,
                                                int* __restrict__ partials) {
    const int t = threadIdx.x;
    const int r = blockIdx.x * 1024 + t;
    int s = 0;
    if (r < NN) {
        const int4* c4 = (const int4*)(counts2 + (size_t)r * 16);
        int4 a = c4[0], b = c4[1], c = c4[2], d = c4[3];
        s = a.x + a.y + a.z + a.w + b.x + b.y + b.z + b.w
          + c.x + c.y + c.z + c.w + d.x + d.y + d.z + d.w;
        s = (s + 15) & ~15;
    }
    __shared__ int buf[1024];
    buf[t] = s;
    __syncthreads();
    for (int off = 1; off < 1024; off <<= 1) {
        int v = (t >= off) ? buf[t - off] : 0;
        __syncthreads();
        buf[t] += v;
        __syncthreads();
    }
    if (r < NN) rp[r] = buf[t] - s;
    if (t == 1023) partials[blockIdx.x] = buf[1023];
}

__global__ __launch_bounds__(64) void k_scanB(int* __restrict__ partials,
                                              int* __restrict__ rp) {
    __shared__ int buf[64];
    int t = threadIdx.x;
    int v = (t < SCAN_BLOCKS) ? partials[t] : 0;
    buf[t] = v;
    __syncthreads();
    for (int off = 1; off < 64; off <<= 1) {
        int x = (t >= off) ? buf[t - off] : 0;
        __syncthreads();
        buf[t] += x;
        __syncthreads();
    }
    if (t < SCAN_BLOCKS) partials[t] = buf[t] - v;
    if (t == 63) rp[NN] = buf[63];
}

__global__ __launch_bounds__(1024) void k_scanC(const int* __restrict__ counts2,
                                                int* __restrict__ rp,
                                                int* __restrict__ cur2,
                                                const int* __restrict__ partials) {
    const int t = threadIdx.x;
    const int r = blockIdx.x * 1024 + t;
    if (r < NN) {
        const int off = partials[blockIdx.x];
        const int base = rp[r] + off;
        rp[r] = base;
        const int4* c4 = (const int4*)(counts2 + (size_t)r * 16);
        int4 ca = c4[0], cb = c4[1], cc = c4[2], cd = c4[3];
        int cnt[16] = {ca.x, ca.y, ca.z, ca.w, cb.x, cb.y, cb.z, cb.w,
                       cc.x, cc.y, cc.z, cc.w, cd.x, cd.y, cd.z, cd.w};
        int out[16];
        int rs = 0;
        #pragma unroll
        for (int b = 0; b < 16; ++b) { out[b] = base + rs; rs += cnt[b]; }
        int4* o4 = (int4*)(cur2 + (size_t)r * 16);
        o4[0] = make_int4(out[0],  out[1],  out[2],  out[3]);
        o4[1] = make_int4(out[4],  out[5],  out[6],  out[7]);
        o4[2] = make_int4(out[8],  out[9],  out[10], out[11]);
        o4[3] = make_int4(out[12], out[13], out[14], out[15]);
    }
}

// ---------------- GEMM1 (MFMA + global_load_lds, XOR-swizzled LDS) ----------------
// Linear LDS dest (gload_lds requirement); 16B-granule XOR swizzle slot^(row&3)
// applied to BOTH the global source address and the fragment read -> fragment
// ds_read_b128s hit every bank exactly 8x (conflict-free minimum).

__global__ __launch_bounds__(256, 4) void k_gemm1(const ushort* __restrict__ Xb,
                                                  const ushort* __restrict__ w1bT,
                                                  const float* __restrict__ B,
                                                  ushort* __restrict__ H) {
    __shared__ ushort As[128 * 32];
    __shared__ ushort Bs[128 * 32];
    const int bid = blockIdx.x;
    const int bm = (bid >> 1) * 128;
    const int bn = (bid & 1) * 128;
    const int tid = threadIdx.x;
    const int wid = tid >> 6, lane = tid & 63;
    const int wm = wid >> 1, wn = wid & 1;
    const int lr = lane & 15, lg = lane >> 4;
    const int swz = (lg ^ (lr & 3)) * 8;      // fragment-read granule swizzle

    f32x4 acc[4][4];
    #pragma unroll
    for (int i = 0; i < 4; ++i)
        #pragma unroll
        for (int j = 0; j < 4; ++j)
            acc[i][j] = (f32x4){0.f, 0.f, 0.f, 0.f};

    for (int kt = 0; kt < DI; kt += 32) {
        #pragma unroll
        for (int c = 0; c < 2; ++c) {
            int i = c * 256 + tid;
            int row = i >> 2, slot = i & 3;
            int ss = slot ^ (row & 3);        // source pre-swizzle
            const ushort* g = Xb + (size_t)(bm + row) * DI + kt + ss * 8;
            gload16(g, As + (size_t)(c * 256 + wid * 64) * 8);
        }
        #pragma unroll
        for (int c = 0; c < 2; ++c) {
            int i = c * 256 + tid;
            int row = i >> 2, slot = i & 3;
            int ss = slot ^ (row & 3);
            const ushort* g = w1bT + (size_t)(bn + row) * DI + kt + ss * 8;
            gload16(g, Bs + (size_t)(c * 256 + wid * 64) * 8);
        }
        __syncthreads();

        short8 a[4], b[4];
        #pragma unroll
        for (int f = 0; f < 4; ++f) {
            a[f] = *(short8*)&As[(wm * 64 + f * 16 + lr) * 32 + swz];
            b[f] = *(short8*)&Bs[(wn * 64 + f * 16 + lr) * 32 + swz];
        }
        #pragma unroll
        for (int i = 0; i < 4; ++i)
            #pragma unroll
            for (int j = 0; j < 4; ++j)
                acc[i][j] = __builtin_amdgcn_mfma_f32_16x16x32_bf16(a[i], b[j], acc[i][j], 0, 0, 0);
        __syncthreads();
    }

    #pragma unroll
    for (int i = 0; i < 4; ++i) {
        int r0 = bm + wm * 64 + i * 16 + lg * 4;
        #pragma unroll
        for (int j = 0; j < 4; ++j) {
            int col = bn + wn * 64 + j * 16 + lr;
            float bias = B[col];
            #pragma unroll
            for (int e = 0; e < 4; ++e) {
                int r = r0 + e;
                if (r < NN) H[(size_t)r * DH + col] = f2b(acc[i][j][e] + bias);
            }
        }
    }
}

// ---------------- scatter: rc32 + bf16 evb, XCD-windowed, 2-way cursor atomics ----------------

__global__ __launch_bounds__(256) void k_scatter(const uint* __restrict__ rc32,
                                                 const ushort* __restrict__ evb,
                                                 int* __restrict__ cur2,
                                                 uint* __restrict__ e4) {
    const int g = blockIdx.x & 7;
    const uint lo = g * (NN / 8), hi = lo + (NN / 8);
    const uint4* rc4 = (const uint4*)rc32;
    for (int q = (blockIdx.x >> 3) * 256 + (int)threadIdx.x; q < NE / 4;
         q += (SC_BLOCKS / 8) * 256) {
        uint4 t = rc4[q];
        #pragma unroll
        for (int e = 0; e < 4; ++e) {
            uint rc = (e == 0) ? t.x : (e == 1) ? t.y : (e == 2) ? t.z : t.w;
            uint rr = rc >> 16;
            if (rr >= lo && rr < hi) {
                uint c = rc & 0xffffu;
                uint vb = evb[q * 4 + e];
                int p = atomicAdd(&cur2[(rr << 4) | (c >> 12)], 1);
                e4[p] = c | (vb << 16);
            }
        }
    }
}

// ---------------- fused SpMM1 + ReLU + GEMM2(MFMA) — r13/r15 version ----------------

__global__ __launch_bounds__(256) void k_srg(const int* __restrict__ rp,
                                             const uint* __restrict__ e4,
                                             const ushort* __restrict__ H,
                                             const ushort* __restrict__ w2bT,
                                             const float* __restrict__ B2,
                                             ushort* __restrict__ H2) {
    __shared__ ushort hs[16][264];
    const int tid = threadIdx.x;
    const int w = tid >> 6, lane = tid & 63;
    const int half = lane >> 5;
    const int dl = lane & 31;
    const ushort* gbase = H + dl * 8;
    const uint4* eq = (const uint4*)e4;

    #pragma unroll
    for (int q = 0; q < 4; ++q) {
        const int r = blockIdx.x * 16 + w * 4 + q;
        const int s = rp[r], e = rp[r + 1];
        float a[8] = {0.f, 0.f, 0.f, 0.f, 0.f, 0.f, 0.f, 0.f};

        int qi = s >> 2;
        uint4 q0 = eq[qi], q1 = eq[qi + 1], q2 = eq[qi + 2], q3 = eq[qi + 3];
        for (int i = s; i < e; i += 16) {
            uint u[8];
            u[0] = half ? q0.y : q0.x;  u[1] = half ? q0.w : q0.z;
            u[2] = half ? q1.y : q1.x;  u[3] = half ? q1.w : q1.z;
            u[4] = half ? q2.y : q2.x;  u[5] = half ? q2.w : q2.z;
            u[6] = half ? q3.y : q3.x;  u[7] = half ? q3.w : q3.z;
            uint4 hw[8];
            #pragma unroll
            for (int k = 0; k < 8; ++k)
                hw[k] = *(const uint4*)(gbase + (size_t)(u[k] & 0xffffu) * DH);
            qi += 4;
            q0 = eq[qi]; q1 = eq[qi + 1]; q2 = eq[qi + 2]; q3 = eq[qi + 3];
            #pragma unroll
            for (int k = 0; k < 8; ++k) {
                float v = __uint_as_float(u[k] & 0xffff0000u);
                uint w0 = hw[k].x, w1 = hw[k].y, w2 = hw[k].z, w3 = hw[k].w;
                a[0] += v * __uint_as_float(w0 << 16);
                a[1] += v * __uint_as_float(w0 & 0xffff0000u);
                a[2] += v * __uint_as_float(w1 << 16);
                a[3] += v * __uint_as_float(w1 & 0xffff0000u);
                a[4] += v * __uint_as_float(w2 << 16);
                a[5] += v * __uint_as_float(w2 & 0xffff0000u);
                a[6] += v * __uint_as_float(w3 << 16);
                a[7] += v * __uint_as_float(w3 & 0xffff0000u);
            }
        }
        #pragma unroll
        for (int d = 0; d < 8; ++d) a[d] += __shfl_xor(a[d], 32);
        if (half == 0) {
            short8 o;
            #pragma unroll
            for (int d = 0; d < 8; ++d) o[d] = (short)f2b(fmaxf(a[d], 0.f));
            *(short8*)&hs[w * 4 + q][dl * 8] = o;
        }
    }
    __syncthreads();

    const int lr = lane & 15, lg = lane >> 4;
    f32x4 acc = (f32x4){0.f, 0.f, 0.f, 0.f};
    #pragma unroll
    for (int kt = 0; kt < DH; kt += 32) {
        short8 af = *(short8*)&hs[lr][kt + lg * 8];
        short8 bf = *(const short8*)(w2bT + (size_t)(w * 16 + lr) * DH + kt + lg * 8);
        acc = __builtin_amdgcn_mfma_f32_16x16x32_bf16(af, bf, acc, 0, 0, 0);
    }
    const int col = w * 16 + lr;
    const float bias = B2[col];
    #pragma unroll
    for (int e = 0; e < 4; ++e) {
        int row = blockIdx.x * 16 + lg * 4 + e;
        H2[(size_t)row * DO + col] = f2b(acc[e] + bias);
    }
}

// ---------------- SpMM2: out = A @ h2 (h2 3.2 MB L2-fits; e4 read 1x) ----------------

__global__ __launch_bounds__(256) void k_spmm_out(const int* __restrict__ rp,
                                                  const uint* __restrict__ e4,
                                                  const ushort* __restrict__ H2,
                                                  float* __restrict__ OUT) {
    const int r = blockIdx.x * 4 + (threadIdx.x >> 6);
    const int lane = threadIdx.x & 63;
    const int slot = lane >> 3;
    const int dq = lane & 7;
    const int s = rp[r], e = rp[r + 1];
    const ushort* base = H2 + dq * 8;
    float a[8] = {0.f, 0.f, 0.f, 0.f, 0.f, 0.f, 0.f, 0.f};

    for (int i = s; i < e; i += 16) {
        uint2 u = *(const uint2*)(e4 + i + 2 * slot);
        short8 h0 = *(const short8*)(base + (size_t)(u.x & 0xffffu) * DO);
        short8 h1 = *(const short8*)(base + (size_t)(u.y & 0xffffu) * DO);
        float v0 = __uint_as_float(u.x & 0xffff0000u);
        float v1 = __uint_as_float(u.y & 0xffff0000u);
        #pragma unroll
        for (int d = 0; d < 8; ++d)
            a[d] += v0 * b2f((ushort)h0[d]) + v1 * b2f((ushort)h1[d]);
    }
    #pragma unroll
    for (int d = 0; d < 8; ++d) {
        a[d] += __shfl_xor(a[d], 8);
        a[d] += __shfl_xor(a[d], 16);
        a[d] += __shfl_xor(a[d], 32);
    }
    if (slot == 0) {
        float* o = OUT + (size_t)r * DO + dq * 8;
        *(float4*)o       = make_float4(a[0], a[1], a[2], a[3]);
        *(float4*)(o + 4) = make_float4(a[4], a[5], a[6], a[7]);
    }
}

// ---------------- launch ----------------

extern "C" void kernel_launch(void* const* d_in, const int* in_sizes, int n_in,
                              void* d_out, int out_size, void* d_ws, size_t ws_size,
                              hipStream_t stream) {
    const float* x  = (const float*)d_in[0];
    const int*   er = (const int*)d_in[1];
    const int*   ec = (const int*)d_in[2];
    const float* ev = (const float*)d_in[3];
    const float* W1 = (const float*)d_in[4];
    const float* b1 = (const float*)d_in[5];
    const float* W2 = (const float*)d_in[6];
    const float* b2 = (const float*)d_in[7];
    float* out = (float*)d_out;

    char* ws = (char*)d_ws;
    // Aliasing: e4 (9.6 MB) overlays Xb (dead after gemm1; memset+scatter run
    // after). rc32 (6.4 MB) overlays h2 (h2 first written by k_srg, which runs
    // after scatter has finished reading rc32).
    ushort* Xb  = (ushort*)ws;
    uint*   e4  = (uint*)ws;
    ws += (size_t)NN * DI * 2;                                               // 51.2 MB
    ushort* h1  = (ushort*)ws; ws += (size_t)NN * DH * 2;                    // 25.6 MB
    ushort* h2  = (ushort*)ws;
    uint*   rc32 = (uint*)ws;  ws += (size_t)NN * DO * 2;                    //  6.4 MB
    int* counts2 = (int*)ws;   ws += ((size_t)NC * 4 + 255) & ~(size_t)255;  //  3.2 MB
    int* rp     = (int*)ws;    ws += ((size_t)(NN + 1) * 4 + 255) & ~(size_t)255;
    int* cur2   = (int*)ws;    ws += ((size_t)NC * 4 + 255) & ~(size_t)255;  //  3.2 MB
    int* partials = (int*)ws;  ws += 256;
    ushort* w1bT = (ushort*)ws; ws += ((size_t)DI * DH * 2 + 255) & ~(size_t)255;
    ushort* w2bT = (ushort*)ws; ws += ((size_t)DH * DO * 2 + 255) & ~(size_t)255;
    ushort* evb  = (ushort*)ws; ws += ((size_t)NE * 2 + 255) & ~(size_t)255;  // 3.2 MB

    hipMemsetAsync(counts2, 0, (size_t)NC * 4, stream);
    k_prep<<<2048, 256, 0, stream>>>(x, Xb, W1, w1bT, W2, w2bT,
                                     er, ec, ev, counts2, rc32, evb);
    k_scanA<<<SCAN_BLOCKS, 1024, 0, stream>>>(counts2, rp, partials);
    k_scanB<<<1, 64, 0, stream>>>(partials, rp);
    k_scanC<<<SCAN_BLOCKS, 1024, 0, stream>>>(counts2, rp, cur2, partials);
    k_gemm1<<<G1_BLOCKS, 256, 0, stream>>>(Xb, w1bT, b1, h1);
    hipMemsetAsync(e4, 0, (size_t)E4_CAP * 4, stream);      // after gemm1 (aliases Xb)
    k_scatter<<<SC_BLOCKS, 256, 0, stream>>>(rc32, evb, cur2, e4);
    k_srg<<<NN / 16, 256, 0, stream>>>(rp, e4, h1, w2bT, b2, h2);
    k_spmm_out<<<NN / 4, 256, 0, stream>>>(rp, e4, h2, out);
}